// Round 3
// baseline (41.988 us; speedup 1.0000x reference)
//
#include <hip/hip_runtime.h>
#include <math.h>

#define K_TOP 16
#define D_DIM 1024
#define ROWS_PER_BLOCK 4   // one row per wave, 4 waves per 256-thread block

typedef float f32x4 __attribute__((ext_vector_type(4)));  // native clang vec

// Each wave owns one (s,r) row q = blockIdx.x*4 + wave:
//   1) selection: lane owns d = lane*16 + j (j=0..15), f32x4 loads,
//      16 rounds of {per-lane masked argmax -> 64-lane butterfly argmax},
//      tie-break prefers smaller global index.
//   2) rank-sort the 16 winners ascending by index (reference does
//      top_k(idx) + reverse = ascending index order).
//   3) wave writes its own 16x1024 one-hot block, nontemporal f32x4 stores.
__global__ __launch_bounds__(256) void dps_topk_kernel(
    const float* __restrict__ logits,  // (64, 1024)
    const float* __restrict__ gn,      // (32, 64, 1024)
    float* __restrict__ out)           // (32, 64, 16, 1024)
{
    const int tid  = threadIdx.x;
    const int lane = tid & 63;
    const int wave = tid >> 6;
    const int q    = blockIdx.x * ROWS_PER_BLOCK + wave;
    const int r    = q & 63;

    __shared__ int sel_lds[ROWS_PER_BLOCK][K_TOP];

    // ---- load + perturb: lane owns 16 consecutive elements (64 B) ----
    float v[16];
    {
        const f32x4* l4 = reinterpret_cast<const f32x4*>(
            logits + (size_t)r * D_DIM + lane * 16);
        const f32x4* g4 = reinterpret_cast<const f32x4*>(
            gn + (size_t)q * D_DIM + lane * 16);
        #pragma unroll
        for (int c = 0; c < 4; ++c) {
            const f32x4 a = l4[c];
            const f32x4 b = g4[c];
            v[c * 4 + 0] = a.x + b.x;
            v[c * 4 + 1] = a.y + b.y;
            v[c * 4 + 2] = a.z + b.z;
            v[c * 4 + 3] = a.w + b.w;
        }
    }

    // ---- 16 rounds of wave-wide argmax ----
    unsigned chosen = 0;   // bitmask of already-taken j's in THIS lane
    int my_sel = 0;        // lane k ends up holding round-k winner's index
    for (int round = 0; round < K_TOP; ++round) {
        float bv = -INFINITY;
        int   bi = 0x7fffffff;
        #pragma unroll
        for (int j = 0; j < 16; ++j) {
            if (!(chosen & (1u << j))) {
                // strict > keeps smaller j (= smaller global index) on tie
                if (v[j] > bv) { bv = v[j]; bi = lane * 16 + j; }
            }
        }
        #pragma unroll
        for (int off = 32; off > 0; off >>= 1) {
            const float ov = __shfl_xor(bv, off);
            const int   oi = __shfl_xor(bi, off);
            if (ov > bv || (ov == bv && oi < bi)) { bv = ov; bi = oi; }
        }
        if (lane == (bi >> 4)) chosen |= 1u << (bi & 15);  // owner retires it
        if (lane == round)     my_sel = bi;
    }

    // ---- sort the 16 winners ascending by index via rank ----
    int rank = 0;
    #pragma unroll
    for (int j = 0; j < K_TOP; ++j) {
        const int other = __shfl(my_sel, j);
        rank += (other < my_sel) ? 1 : 0;
    }
    if (lane < K_TOP) sel_lds[wave][rank] = my_sel;
    __syncthreads();   // guarantees LDS visibility before reads

    // ---- write own row's 16x1024 one-hot block (nontemporal) ----
    float* orow = out + (size_t)q * (K_TOP * D_DIM);
    #pragma unroll
    for (int k = 0; k < K_TOP; ++k) {
        const int s  = sel_lds[wave][k];   // wave-uniform
        const int sv = s >> 2;             // which f32x4 holds the 1
        f32x4 hot;
        hot.x = ((s & 3) == 0) ? 1.0f : 0.0f;
        hot.y = ((s & 3) == 1) ? 1.0f : 0.0f;
        hot.z = ((s & 3) == 2) ? 1.0f : 0.0f;
        hot.w = ((s & 3) == 3) ? 1.0f : 0.0f;
        const f32x4 zero = {0.f, 0.f, 0.f, 0.f};
        f32x4* krow = reinterpret_cast<f32x4*>(orow + k * D_DIM);
        #pragma unroll
        for (int c = 0; c < 4; ++c) {
            const int f4idx = c * 64 + lane;           // f32x4 index in row
            const f32x4 val = (f4idx == sv) ? hot : zero;
            __builtin_nontemporal_store(val, krow + f4idx);
        }
    }
}

extern "C" void kernel_launch(void* const* d_in, const int* in_sizes, int n_in,
                              void* d_out, int out_size, void* d_ws, size_t ws_size,
                              hipStream_t stream) {
    const float* logits = (const float*)d_in[0];  // (64, 1024) f32
    const float* gn     = (const float*)d_in[1];  // (32, 64, 1024) f32
    float* out          = (float*)d_out;          // (32, 64, 16, 1024) f32

    dps_topk_kernel<<<dim3(2048 / ROWS_PER_BLOCK), dim3(256), 0, stream>>>(
        logits, gn, out);
}